// Round 4
// baseline (196.168 us; speedup 1.0000x reference)
//
#include <hip/hip_runtime.h>
#include <hip/hip_bf16.h>
#include <stdint.h>

// GCN fused: out = relu(A @ (H @ W^T) + b),  B=8, N=2048, L=4, D=256.
// hwt_kernel: HWT = H@W^T -> bf16, stored transposed (k-contiguous).
// gemm_fp32a: 128x256 tile, BK=64, 8 waves, 8-phase software-pipelined loop.
//   A is read fp32 directly from d_in and converted in-kernel (reg-stage ->
//   swizzled ds_write), eliminating the 201 MB cvt pre-pass. B via gl16 with
//   pre-swizzled source. Frag reads one phase ahead; 4 barriers/iter.

typedef __bf16 bf16;
typedef __attribute__((ext_vector_type(8))) __bf16 bf16x8;
typedef __attribute__((ext_vector_type(4))) __bf16 bf16x4;
typedef __attribute__((ext_vector_type(4))) float f32x4;

#define B_  8
#define N_  2048
#define L_  4
#define D_  256
#define LD_ 1024
#define BK  64
#define NT  (N_ / BK)   // 32 K-tiles
#define NI  (NT / 2)    // 16 iterations

__device__ __forceinline__ void gl16(const char* g, char* l) {
  __builtin_amdgcn_global_load_lds((const __attribute__((address_space(1))) void*)g,
                                   (__attribute__((address_space(3))) void*)l, 16, 0, 0);
}

__device__ inline void cvt_store8(const float* __restrict__ s, bf16* d) {
  float4 x = ((const float4*)s)[0];
  float4 y = ((const float4*)s)[1];
  bf16x8 o;
  o[0] = (bf16)x.x; o[1] = (bf16)x.y; o[2] = (bf16)x.z; o[3] = (bf16)x.w;
  o[4] = (bf16)y.x; o[5] = (bf16)y.y; o[6] = (bf16)y.z; o[7] = (bf16)y.w;
  *(bf16x8*)d = o;
}

// ---------------- kernel 1: HWT_T[b][l*256+e][m] = sum_d H[b][m][l][d]*W[e][d] ----
__global__ __launch_bounds__(256) void hwt_kernel(const float* __restrict__ H,
                                                  const float* __restrict__ Wm,
                                                  bf16* __restrict__ outT) {
  const int bid = blockIdx.x;          // 8 * 64 * 2 = 1024 blocks
  const int b   = bid >> 7;
  const int rem = bid & 127;
  const int te  = rem & 1;
  const int tr  = rem >> 1;
  const int r0  = tr * 128;
  const int e0  = te * 128;

  __shared__ __attribute__((aligned(16))) bf16 Ah[128 * 64];
  __shared__ __attribute__((aligned(16))) bf16 Wt[128 * 64];

  const int t    = threadIdx.x;
  const int lane = t & 63;
  const int wave = t >> 6;
  const int wr = wave >> 1, wc = wave & 1;

  const f32x4 zero = {0.f, 0.f, 0.f, 0.f};
  f32x4 acc[4][4];
  for (int m = 0; m < 4; ++m)
    for (int n = 0; n < 4; ++n) acc[m][n] = zero;

  const float* Hb = H + (size_t)b * (N_ * L_ * D_);
  const int mrow = t >> 3;
  const int colb = (t & 7) * 8;

  for (int k0 = 0; k0 < D_; k0 += 64) {
#pragma unroll
    for (int i = 0; i < 4; ++i) {
      const int r_local = mrow * 4 + i;     // l = i, m_local = mrow
      cvt_store8(Hb + (size_t)(r0 + r_local) * D_ + k0 + colb,
                 Ah + (size_t)t * 8 + i * 2048);
      const int erow = i * 32 + mrow;
      cvt_store8(Wm + (size_t)(e0 + erow) * D_ + k0 + colb,
                 Wt + (size_t)t * 8 + i * 2048);
    }
    __syncthreads();
#pragma unroll
    for (int kk = 0; kk < 2; ++kk) {
      bf16x8 af[4], bg[4];
#pragma unroll
      for (int m = 0; m < 4; ++m)
        af[m] = *(const bf16x8*)&Ah[(wr * 64 + m * 16 + (lane & 15)) * 64 + kk * 32 + (lane >> 4) * 8];
#pragma unroll
      for (int n = 0; n < 4; ++n)
        bg[n] = *(const bf16x8*)&Wt[(wc * 64 + n * 16 + (lane & 15)) * 64 + kk * 32 + (lane >> 4) * 8];
#pragma unroll
      for (int m = 0; m < 4; ++m)
#pragma unroll
        for (int n = 0; n < 4; ++n)
          acc[m][n] = __builtin_amdgcn_mfma_f32_16x16x32_bf16(af[m], bg[n], acc[m][n], 0, 0, 0);
    }
    __syncthreads();
  }

  bf16* ob = outT + (size_t)b * (LD_ * N_);
  const int m0 = tr * 32;
#pragma unroll
  for (int m16 = 0; m16 < 4; ++m16) {
    const int qrow = wr * 64 + m16 * 16 + ((lane >> 4) << 2);
    const int l  = qrow >> 5;
    const int ml = qrow & 31;
#pragma unroll
    for (int n = 0; n < 4; ++n) {
      const int e = e0 + wc * 64 + n * 16 + (lane & 15);
      bf16x4 v;
      v[0] = (bf16)acc[m16][n][0]; v[1] = (bf16)acc[m16][n][1];
      v[2] = (bf16)acc[m16][n][2]; v[3] = (bf16)acc[m16][n][3];
      *(bf16x4*)&ob[(size_t)(l * 256 + e) * N_ + m0 + ml] = v;
    }
  }
}

// ---------------- kernel 2: 128x256-tile pipelined GEMM, fp32 A ----------------
// out[b][n][c] = relu(sum_m A[b][n][m] * HWT[b][c][m] + bias[c&255])
__global__ __launch_bounds__(512, 2) void gemm_fp32a_kernel(
    const float* __restrict__ Af, const bf16* __restrict__ HWT,
    const float* __restrict__ bias, float* __restrict__ out) {

  __shared__ __attribute__((aligned(128))) char smem[98304];  // 2 bufs x (A 16K + B 32K)

  // T1: 512 blocks % 8 == 0 -> xcd = batch
  const int bid = blockIdx.x;
  const int lg  = (bid & 7) * 64 + (bid >> 3);
  const int b   = lg >> 6;
  const int tn  = (lg >> 2) & 15;   // 16 row tiles of 128
  const int tc  = lg & 3;           // 4 col tiles of 256
  const int n0  = tn * 128;
  const int c0  = tc * 256;

  const int t    = threadIdx.x;
  const int lane = t & 63;
  const int w    = t >> 6;
  const int wm   = w >> 2;   // 0..1
  const int wn   = w & 3;    // 0..3
  const int l15  = lane & 15;
  const int cg   = lane >> 4;
  const int sl0  = cg ^ (lane & 7);     // swizzled 16B-slot, kk=0

  // B staging: gl16, linear LDS dest, pre-swizzled global source
  const char* Hb = (const char*)(HWT + (size_t)b * LD_ * N_);
  const int grow  = t >> 3;                        // 0..63
  const int gslot = ((t & 7) ^ (grow & 7)) << 4;
  const char* pB = Hb + (size_t)(c0 + grow) * (N_ * 2) + gslot;
  char* lB = (char*)smem + 16384 + t * 16;         // B region base + t*16

  // A staging: fp32 global -> regs -> cvt -> swizzled ds_write
  const float* Ab = Af + (size_t)b * N_ * N_;
  const int rA = t >> 2;            // 0..127
  const int cq = t & 3;             // 16-col quarter of BK
  const float* pA = Ab + (size_t)(n0 + rA) * N_ + cq * 16;
  char* wA0 = (char*)smem + rA * 128 + ((((2 * cq)     ^ (rA & 7))) << 4);
  char* wA1 = (char*)smem + rA * 128 + ((((2 * cq + 1) ^ (rA & 7))) << 4);

  float4 av0, av1, av2, av3;

#define ALOAD(kt) do {                                                        \
    const float4* ap_ = (const float4*)(pA + (size_t)(kt) * BK);              \
    av0 = ap_[0]; av1 = ap_[1]; av2 = ap_[2]; av3 = ap_[3];                   \
  } while (0)

#define AWRITE(buf) do {                                                      \
    bf16x8 o0_, o1_;                                                          \
    o0_[0]=(bf16)av0.x; o0_[1]=(bf16)av0.y; o0_[2]=(bf16)av0.z;               \
    o0_[3]=(bf16)av0.w; o0_[4]=(bf16)av1.x; o0_[5]=(bf16)av1.y;               \
    o0_[6]=(bf16)av1.z; o0_[7]=(bf16)av1.w;                                   \
    o1_[0]=(bf16)av2.x; o1_[1]=(bf16)av2.y; o1_[2]=(bf16)av2.z;               \
    o1_[3]=(bf16)av2.w; o1_[4]=(bf16)av3.x; o1_[5]=(bf16)av3.y;               \
    o1_[6]=(bf16)av3.z; o1_[7]=(bf16)av3.w;                                   \
    *(bf16x8*)(wA0 + (buf) * 49152) = o0_;                                    \
    *(bf16x8*)(wA1 + (buf) * 49152) = o1_;                                    \
  } while (0)

#define STAGEB(buf, half, kt) do {                                            \
    const char* gp_ = pB + (size_t)((half) * 128) * (N_ * 2)                  \
                      + (size_t)(kt) * (BK * 2);                              \
    char* lp_ = lB + (buf) * 49152 + (half) * 16384;                          \
    gl16(gp_, lp_);                                                           \
    gl16(gp_ + (size_t)64 * (N_ * 2), lp_ + 8192);                            \
  } while (0)

#define LDA(buf, fm, kk)                                                      \
  (*(const bf16x8*)(smem + (buf) * 49152 +                                    \
      (wm * 64 + (fm) * 16 + l15) * 128 + ((sl0 ^ ((kk) * 4)) << 4)))

#define LDB(buf, fn, kk)                                                      \
  (*(const bf16x8*)(smem + (buf) * 49152 + 16384 +                            \
      (wn * 64 + (fn) * 16 + l15) * 128 + ((sl0 ^ ((kk) * 4)) << 4)))

#define MFMA8(fh, AF, BF)                                                     \
  do {                                                                        \
    __builtin_amdgcn_s_setprio(1);                                            \
    _Pragma("unroll")                                                         \
    for (int fm_ = 0; fm_ < 2; ++fm_)                                         \
      _Pragma("unroll")                                                       \
      for (int fn_ = 0; fn_ < 4; ++fn_)                                       \
        acc[(fh) * 2 + fm_][fn_] = __builtin_amdgcn_mfma_f32_16x16x32_bf16(   \
            AF[fm_], BF[fn_], acc[(fh) * 2 + fm_][fn_], 0, 0, 0);             \
    __builtin_amdgcn_s_setprio(0);                                            \
  } while (0)

#define BARRIER() do { __builtin_amdgcn_s_barrier();                          \
                       asm volatile("" ::: "memory"); } while (0)
#define READY_BAR() do {                                                      \
    asm volatile("s_waitcnt vmcnt(0) lgkmcnt(0)" ::: "memory");               \
    __builtin_amdgcn_sched_barrier(0);                                        \
    BARRIER(); } while (0)
#define VM4() asm volatile("s_waitcnt vmcnt(4)" ::: "memory")

  f32x4 acc[4][4];
#pragma unroll
  for (int i_ = 0; i_ < 4; ++i_)
#pragma unroll
    for (int j_ = 0; j_ < 4; ++j_) acc[i_][j_] = (f32x4){0.f, 0.f, 0.f, 0.f};

  bf16x8 aX[2], aY[2], bA[4], bB[4];

  // prologue: buf0 <- kt0 (A via regs, B via gl16); prime frag reads
  ALOAD(0);
  STAGEB(0, 0, 0); STAGEB(0, 1, 0);
  VM4();
  AWRITE(0);
  READY_BAR();
#pragma unroll
  for (int fm = 0; fm < 2; ++fm) aY[fm] = LDA(0, fm, 0);
#pragma unroll
  for (int fn = 0; fn < 4; ++fn) bA[fn] = LDB(0, fn, 0);

#pragma unroll 1
  for (int i = 0; i < NI; ++i) {
    const int kt1 = 2 * i + 1;
    const int kt2 = (2 * i + 2 < NT) ? 2 * i + 2 : NT - 2;  // tail clamp (unused data)

    // P1: reads aX<-A(0,fh0,kk1), bB<-B(0,kk1); ALOAD kt1; stage B(1,h0);
    //     MFMA (fh0,kk0)
#pragma unroll
    for (int fm = 0; fm < 2; ++fm) aX[fm] = LDA(0, fm, 1);
#pragma unroll
    for (int fn = 0; fn < 4; ++fn) bB[fn] = LDB(0, fn, 1);
    ALOAD(kt1);
    STAGEB(1, 0, kt1);
    MFMA8(0, aY, bA);

    // P2: reads aY<-A(0,fh1,kk0); stage B(1,h1); A-data arrived -> AWRITE buf1;
    //     MFMA (fh0,kk1)
#pragma unroll
    for (int fm = 0; fm < 2; ++fm) aY[fm] = LDA(0, 2 + fm, 0);
    STAGEB(1, 1, kt1);
    VM4();
    AWRITE(1);
    MFMA8(0, aX, bB);

    // P3: reads aX<-A(0,fh1,kk1); MFMA (fh1,kk0); [buf1 ready] vm0+lgkm0+bar
#pragma unroll
    for (int fm = 0; fm < 2; ++fm) aX[fm] = LDA(0, 2 + fm, 1);
    MFMA8(1, aY, bA);
    READY_BAR();

    // P4: reads aY<-A(1,fh0,kk0), bA<-B(1,kk0); MFMA (fh1,kk1); bar [buf0 free]
#pragma unroll
    for (int fm = 0; fm < 2; ++fm) aY[fm] = LDA(1, fm, 0);
#pragma unroll
    for (int fn = 0; fn < 4; ++fn) bA[fn] = LDB(1, fn, 0);
    MFMA8(1, aX, bB);
    BARRIER();

    // P5: reads aX<-A(1,fh0,kk1), bB<-B(1,kk1); ALOAD kt2; stage B(0,h0);
    //     MFMA (fh0,kk0)
#pragma unroll
    for (int fm = 0; fm < 2; ++fm) aX[fm] = LDA(1, fm, 1);
#pragma unroll
    for (int fn = 0; fn < 4; ++fn) bB[fn] = LDB(1, fn, 1);
    ALOAD(kt2);
    STAGEB(0, 0, kt2);
    MFMA8(0, aY, bA);

    // P6: reads aY<-A(1,fh1,kk0); stage B(0,h1); AWRITE buf0; MFMA (fh0,kk1)
#pragma unroll
    for (int fm = 0; fm < 2; ++fm) aY[fm] = LDA(1, 2 + fm, 0);
    STAGEB(0, 1, kt2);
    VM4();
    AWRITE(0);
    MFMA8(0, aX, bB);

    // P7: reads aX<-A(1,fh1,kk1); MFMA (fh1,kk0); [buf0 ready] vm0+lgkm0+bar
#pragma unroll
    for (int fm = 0; fm < 2; ++fm) aX[fm] = LDA(1, 2 + fm, 1);
    MFMA8(1, aY, bA);
    READY_BAR();

    // P8: reads aY<-A(0,fh0,kk0), bA<-B(0,kk0); MFMA (fh1,kk1); bar [buf1 free]
#pragma unroll
    for (int fm = 0; fm < 2; ++fm) aY[fm] = LDA(0, fm, 0);
#pragma unroll
    for (int fn = 0; fn < 4; ++fn) bA[fn] = LDB(0, fn, 0);
    MFMA8(1, aX, bB);
    BARRIER();
  }

  // epilogue: + bias, relu, fp32 store
  float* ob = out + (size_t)b * N_ * LD_;
  const int orow0 = n0 + wm * 64 + cg * 4;
  const int ocol0 = c0 + wn * 64 + l15;
#pragma unroll
  for (int fm = 0; fm < 4; ++fm) {
    const int r = orow0 + fm * 16;
#pragma unroll
    for (int fn = 0; fn < 4; ++fn) {
      const int c = ocol0 + fn * 16;
      const float bv = bias[c & 255];
      const f32x4 v = acc[fm][fn];
#pragma unroll
      for (int j = 0; j < 4; ++j) {
        const float x = v[j] + bv;
        ob[(size_t)(r + j) * LD_ + c] = x > 0.f ? x : 0.f;
      }
    }
  }
#undef ALOAD
#undef AWRITE
#undef STAGEB
#undef LDA
#undef LDB
#undef MFMA8
#undef BARRIER
#undef READY_BAR
#undef VM4
}

extern "C" void kernel_launch(void* const* d_in, const int* in_sizes, int n_in,
                              void* d_out, int out_size, void* d_ws, size_t ws_size,
                              hipStream_t stream) {
  const float* H    = (const float*)d_in[0];   // prop_state (B,N,L,D)
  const float* A    = (const float*)d_in[1];   // (B,N,N)
  const float* Wm   = (const float*)d_in[2];   // (D,D)
  const float* bias = (const float*)d_in[3];   // (D,)
  float* out = (float*)d_out;

  const size_t hwt_bytes = (size_t)B_ * LD_ * N_ * sizeof(bf16);  // 33.5 MB
  if (ws_size < hwt_bytes) return;

  bf16* hwt = (bf16*)d_ws;

  hwt_kernel<<<dim3(1024), dim3(256), 0, stream>>>(H, Wm, hwt);
  gemm_fp32a_kernel<<<dim3(512), dim3(512), 0, stream>>>(A, hwt, bias, out);
}

// Round 5
// 135.446 us; speedup vs baseline: 1.4483x; 1.4483x over previous
//
#include <hip/hip_runtime.h>
#include <hip/hip_bf16.h>
#include <stdint.h>

// GCN fused: out = relu(A @ (H @ W^T) + b),  B=8, N=2048, L=4, D=256.
// cvt_a: A fp32 -> bf16 (BW roofline).  hwt: HWT = H@W^T bf16 transposed
// (k-contiguous), LDS XOR-swizzled both sides.  gemm8p: 256x256 tile, BK=64,
// 8 waves, software-pipelined 8-phase loop (frag reads one phase ahead,
// counted lgkm waits from dataflow, 4 barriers/iter) — R3's verified kernel.

typedef __bf16 bf16;
typedef __attribute__((ext_vector_type(8))) __bf16 bf16x8;
typedef __attribute__((ext_vector_type(4))) __bf16 bf16x4;
typedef __attribute__((ext_vector_type(4))) float f32x4;

#define B_  8
#define N_  2048
#define L_  4
#define D_  256
#define LD_ 1024
#define BK  64
#define NT  (N_ / BK)   // 32 K-tiles
#define NI  (NT / 2)    // 16 iterations

__device__ __forceinline__ void gl16(const char* g, char* l) {
  __builtin_amdgcn_global_load_lds((const __attribute__((address_space(1))) void*)g,
                                   (__attribute__((address_space(3))) void*)l, 16, 0, 0);
}

__device__ inline void cvt8(const float* __restrict__ s, bf16x8* o) {
  float4 x = ((const float4*)s)[0];
  float4 y = ((const float4*)s)[1];
  (*o)[0] = (bf16)x.x; (*o)[1] = (bf16)x.y; (*o)[2] = (bf16)x.z; (*o)[3] = (bf16)x.w;
  (*o)[4] = (bf16)y.x; (*o)[5] = (bf16)y.y; (*o)[6] = (bf16)y.z; (*o)[7] = (bf16)y.w;
}

// ---------------- kernel 1: A fp32 -> bf16 ----------------
__global__ __launch_bounds__(256) void cvt_a_kernel(const float* __restrict__ src,
                                                    bf16* __restrict__ dst, int n8) {
  int i = blockIdx.x * 256 + threadIdx.x;
  const int stride = gridDim.x * 256;
  for (; i < n8; i += stride) {
    bf16x8 o;
    cvt8(src + (size_t)i * 8, &o);
    *(bf16x8*)(dst + (size_t)i * 8) = o;
  }
}

// ---------------- kernel 2: HWT_T[b][l*256+e][m] = sum_d H[b][m][l][d]*W[e][d] ----
// LDS tiles XOR-swizzled (write slot (t&7)^((t>>3)&7); read slot ^ (row&7)).
__global__ __launch_bounds__(256) void hwt_kernel(const float* __restrict__ H,
                                                  const float* __restrict__ Wm,
                                                  bf16* __restrict__ outT) {
  const int bid = blockIdx.x;          // 8 * 64 * 2 = 1024 blocks
  const int b   = bid >> 7;
  const int rem = bid & 127;
  const int te  = rem & 1;
  const int tr  = rem >> 1;
  const int r0  = tr * 128;
  const int e0  = te * 128;

  __shared__ __attribute__((aligned(16))) char Ah[128 * 128];
  __shared__ __attribute__((aligned(16))) char Wt[128 * 128];

  const int t    = threadIdx.x;
  const int lane = t & 63;
  const int wave = t >> 6;
  const int wr = wave >> 1, wc = wave & 1;
  const int l15 = lane & 15;
  const int cg  = lane >> 4;

  const f32x4 zero = {0.f, 0.f, 0.f, 0.f};
  f32x4 acc[4][4];
  for (int m = 0; m < 4; ++m)
    for (int n = 0; n < 4; ++n) acc[m][n] = zero;

  const float* Hb = H + (size_t)b * (N_ * L_ * D_);
  const int mrow = t >> 3;          // 0..31
  const int colb = (t & 7) * 8;
  // swizzled write byte offset: row = (t>>3)+i*32, slot = (t&7)^(row&7)
  const int woff = (t >> 3) * 128 + (((t & 7) ^ ((t >> 3) & 7)) << 4);

  for (int k0 = 0; k0 < D_; k0 += 64) {
#pragma unroll
    for (int i = 0; i < 4; ++i) {
      const int r_local = mrow * 4 + i;     // l = i, m_local = mrow
      bf16x8 oa, ow;
      cvt8(Hb + (size_t)(r0 + r_local) * D_ + k0 + colb, &oa);
      const int erow = i * 32 + mrow;
      cvt8(Wm + (size_t)(e0 + erow) * D_ + k0 + colb, &ow);
      *(bf16x8*)(Ah + woff + i * 4096) = oa;
      *(bf16x8*)(Wt + woff + i * 4096) = ow;
    }
    __syncthreads();
#pragma unroll
    for (int kk = 0; kk < 2; ++kk) {
      bf16x8 af[4], bg[4];
#pragma unroll
      for (int m = 0; m < 4; ++m) {
        const int row = wr * 64 + m * 16 + l15;
        af[m] = *(const bf16x8*)&Ah[row * 128 + (((kk * 4 + cg) ^ (row & 7)) << 4)];
      }
#pragma unroll
      for (int n = 0; n < 4; ++n) {
        const int row = wc * 64 + n * 16 + l15;
        bg[n] = *(const bf16x8*)&Wt[row * 128 + (((kk * 4 + cg) ^ (row & 7)) << 4)];
      }
#pragma unroll
      for (int m = 0; m < 4; ++m)
#pragma unroll
        for (int n = 0; n < 4; ++n)
          acc[m][n] = __builtin_amdgcn_mfma_f32_16x16x32_bf16(af[m], bg[n], acc[m][n], 0, 0, 0);
    }
    __syncthreads();
  }

  bf16* ob = outT + (size_t)b * (LD_ * N_);
  const int m0 = tr * 32;
#pragma unroll
  for (int m16 = 0; m16 < 4; ++m16) {
    const int qrow = wr * 64 + m16 * 16 + (cg << 2);
    const int l  = qrow >> 5;
    const int ml = qrow & 31;
#pragma unroll
    for (int n = 0; n < 4; ++n) {
      const int e = e0 + wc * 64 + n * 16 + l15;
      bf16x4 v;
      v[0] = (bf16)acc[m16][n][0]; v[1] = (bf16)acc[m16][n][1];
      v[2] = (bf16)acc[m16][n][2]; v[3] = (bf16)acc[m16][n][3];
      *(bf16x4*)&ob[(size_t)(l * 256 + e) * N_ + m0 + ml] = v;
    }
  }
}

// ---------------- kernel 3: pipelined 256x256-tile 8-phase GEMM ----------------
// out[b][n][c] = relu(sum_m A16[b][n][m] * HWT[b][c][m] + bias[c&255])
__global__ __launch_bounds__(512, 2) void gemm8p_kernel(
    const bf16* __restrict__ A16, const bf16* __restrict__ HWT,
    const float* __restrict__ bias, float* __restrict__ out) {

  __shared__ __attribute__((aligned(128))) char smem[131072];

  // T1: 256 blocks % 8 == 0 -> xcd = batch
  const int bid = blockIdx.x;
  const int lg  = (bid & 7) * 32 + (bid >> 3);
  const int b   = lg >> 5;
  const int tn  = (lg >> 2) & 7;   // M tile (output rows, n-dim)
  const int tc  = lg & 3;          // N tile (output cols, c-dim)
  const int n0  = tn * 256;
  const int c0  = tc * 256;

  const int t    = threadIdx.x;
  const int lane = t & 63;
  const int w    = t >> 6;
  const int wm   = w >> 2;   // 0..1
  const int wn   = w & 3;    // 0..3
  const int l15  = lane & 15;
  const int cg   = lane >> 4;
  const int sl0  = cg ^ (lane & 7);     // swizzled 16B-slot for kk=0

  const char* Ab = (const char*)(A16 + (size_t)b * N_ * N_);
  const char* Hb = (const char*)(HWT + (size_t)b * LD_ * N_);
  const int  grow  = t >> 3;                       // 0..63
  const int  gslot = ((t & 7) ^ (grow & 7)) << 4;  // pre-swizzled source slot
  const char* pA = Ab + (size_t)(n0 + grow) * (N_ * 2) + gslot;
  const char* pB = Hb + (size_t)(c0 + grow) * (N_ * 2) + gslot;
  char* lbase = (char*)smem + t * 16;

#define STAGE(buf, isB, half, kt) do {                                        \
    const char* gp_ = ((isB) ? pB : pA) + (size_t)((half) * 128) * (N_ * 2)   \
                      + (size_t)(kt) * (BK * 2);                              \
    char* lp_ = lbase + (buf) * 65536 + (isB) * 32768 + (half) * 16384;       \
    gl16(gp_, lp_);                                                           \
    gl16(gp_ + (size_t)64 * (N_ * 2), lp_ + 8192);                            \
  } while (0)

#define LDA(buf, mh, fm, kk)                                                  \
  (*(const bf16x8*)(smem + (buf) * 65536 +                                    \
      (wm * 128 + (mh) * 64 + (fm) * 16 + l15) * 128 +                        \
      ((sl0 ^ ((kk) * 4)) << 4)))

#define LDB(buf, fn, kk)                                                      \
  (*(const bf16x8*)(smem + (buf) * 65536 + 32768 +                            \
      (wn * 64 + (fn) * 16 + l15) * 128 +                                     \
      ((sl0 ^ ((kk) * 4)) << 4)))

#define MFMA16(base, AF, BF)                                                  \
  do {                                                                        \
    __builtin_amdgcn_s_setprio(1);                                            \
    _Pragma("unroll")                                                         \
    for (int fm_ = 0; fm_ < 4; ++fm_)                                         \
      _Pragma("unroll")                                                       \
      for (int fn_ = 0; fn_ < 4; ++fn_)                                       \
        acc[(base) + fm_][fn_] = __builtin_amdgcn_mfma_f32_16x16x32_bf16(     \
            AF[fm_], BF[fn_], acc[(base) + fm_][fn_], 0, 0, 0);               \
    __builtin_amdgcn_s_setprio(0);                                            \
  } while (0)

#define BARRIER() do { __builtin_amdgcn_s_barrier();                          \
                       asm volatile("" ::: "memory"); } while (0)
#define VMCNT0_BAR() do {                                                     \
    asm volatile("s_waitcnt vmcnt(0)" ::: "memory");                          \
    __builtin_amdgcn_sched_barrier(0);                                        \
    BARRIER(); } while (0)

  f32x4 acc[8][4];
#pragma unroll
  for (int i_ = 0; i_ < 8; ++i_)
#pragma unroll
    for (int j_ = 0; j_ < 4; ++j_) acc[i_][j_] = (f32x4){0.f, 0.f, 0.f, 0.f};

  bf16x8 aX[4], aY[4], bA[4], bB[4];

  // prologue: buf0 <- kt0 fully; then initial frag reads (feed P1's MFMA)
  STAGE(0, 0, 0, 0); STAGE(0, 0, 1, 0); STAGE(0, 1, 0, 0); STAGE(0, 1, 1, 0);
  VMCNT0_BAR();
#pragma unroll
  for (int fm = 0; fm < 4; ++fm) aY[fm] = LDA(0, 0, fm, 0);
#pragma unroll
  for (int fn = 0; fn < 4; ++fn) bA[fn] = LDB(0, fn, 0);

#pragma unroll 1
  for (int i = 0; i < NI; ++i) {
    const int kt1 = 2 * i + 1;
    const int kt2 = (2 * i + 2 < NT) ? 2 * i + 2 : NT - 2;  // clamp: tail stage unused

    // P1: reads aX<-A(b0,mh0,kk1), bB<-B(b0,kk1); stage buf1<-kt1 (A0,A1,B0);
    //     MFMA(mh0,kk0) = aY x bA
#pragma unroll
    for (int fm = 0; fm < 4; ++fm) aX[fm] = LDA(0, 0, fm, 1);
#pragma unroll
    for (int fn = 0; fn < 4; ++fn) bB[fn] = LDB(0, fn, 1);
    STAGE(1, 0, 0, kt1); STAGE(1, 0, 1, kt1); STAGE(1, 1, 0, kt1);
    MFMA16(0, aY, bA);

    // P2: reads aY<-A(b0,mh1,kk0); stage buf1.B1; MFMA(mh0,kk1) = aX x bB
#pragma unroll
    for (int fm = 0; fm < 4; ++fm) aY[fm] = LDA(0, 1, fm, 0);
    STAGE(1, 1, 1, kt1);
    MFMA16(0, aX, bB);

    // P3: reads aX<-A(b0,mh1,kk1); MFMA(mh1,kk0) = aY x bA; [buf1 ready] vmcnt0+BAR
#pragma unroll
    for (int fm = 0; fm < 4; ++fm) aX[fm] = LDA(0, 1, fm, 1);
    MFMA16(4, aY, bA);
    VMCNT0_BAR();

    // P4: reads aY<-A(b1,mh0,kk0), bA<-B(b1,kk0); MFMA(mh1,kk1) = aX x bB;
    //     BAR (buf0 reads all retired -> P5 may re-stage buf0)
#pragma unroll
    for (int fm = 0; fm < 4; ++fm) aY[fm] = LDA(1, 0, fm, 0);
#pragma unroll
    for (int fn = 0; fn < 4; ++fn) bA[fn] = LDB(1, fn, 0);
    MFMA16(4, aX, bB);
    BARRIER();

    // P5: reads aX<-A(b1,mh0,kk1), bB<-B(b1,kk1); stage buf0<-kt2 (A0,A1,B0);
    //     MFMA(mh0,kk0) = aY x bA
#pragma unroll
    for (int fm = 0; fm < 4; ++fm) aX[fm] = LDA(1, 0, fm, 1);
#pragma unroll
    for (int fn = 0; fn < 4; ++fn) bB[fn] = LDB(1, fn, 1);
    STAGE(0, 0, 0, kt2); STAGE(0, 0, 1, kt2); STAGE(0, 1, 0, kt2);
    MFMA16(0, aY, bA);

    // P6: reads aY<-A(b1,mh1,kk0); stage buf0.B1; MFMA(mh0,kk1) = aX x bB
#pragma unroll
    for (int fm = 0; fm < 4; ++fm) aY[fm] = LDA(1, 1, fm, 0);
    STAGE(0, 1, 1, kt2);
    MFMA16(0, aX, bB);

    // P7: reads aX<-A(b1,mh1,kk1); MFMA(mh1,kk0) = aY x bA; [buf0 ready] vmcnt0+BAR
#pragma unroll
    for (int fm = 0; fm < 4; ++fm) aX[fm] = LDA(1, 1, fm, 1);
    MFMA16(4, aY, bA);
    VMCNT0_BAR();

    // P8: reads aY<-A(b0new,mh0,kk0), bA<-B(b0new,kk0); MFMA(mh1,kk1) = aX x bB;
    //     BAR (buf1 reads all retired -> next P1 may re-stage buf1)
#pragma unroll
    for (int fm = 0; fm < 4; ++fm) aY[fm] = LDA(0, 0, fm, 0);
#pragma unroll
    for (int fn = 0; fn < 4; ++fn) bA[fn] = LDB(0, fn, 0);
    MFMA16(4, aX, bB);
    BARRIER();
  }

  // epilogue: + bias, relu, fp32 store
  float* ob = out + (size_t)b * N_ * LD_;
  const int orow0 = n0 + wm * 128 + cg * 4;
  const int ocol0 = c0 + wn * 64 + l15;
#pragma unroll
  for (int mh = 0; mh < 2; ++mh)
#pragma unroll
    for (int fm = 0; fm < 4; ++fm) {
      const int r = orow0 + mh * 64 + fm * 16;
#pragma unroll
      for (int fn = 0; fn < 4; ++fn) {
        const int c = ocol0 + fn * 16;
        const float bv = bias[c & 255];
        const f32x4 v = acc[mh * 4 + fm][fn];
#pragma unroll
        for (int j = 0; j < 4; ++j) {
          const float x = v[j] + bv;
          ob[(size_t)(r + j) * LD_ + c] = x > 0.f ? x : 0.f;
        }
      }
    }
#undef STAGE
#undef LDA
#undef LDB
#undef MFMA16
#undef BARRIER
#undef VMCNT0_BAR
}

extern "C" void kernel_launch(void* const* d_in, const int* in_sizes, int n_in,
                              void* d_out, int out_size, void* d_ws, size_t ws_size,
                              hipStream_t stream) {
  const float* H    = (const float*)d_in[0];   // prop_state (B,N,L,D)
  const float* A    = (const float*)d_in[1];   // (B,N,N)
  const float* Wm   = (const float*)d_in[2];   // (D,D)
  const float* bias = (const float*)d_in[3];   // (D,)
  float* out = (float*)d_out;

  const size_t hwt_bytes = (size_t)B_ * LD_ * N_ * sizeof(bf16);  // 33.5 MB
  const size_t a16_bytes = (size_t)B_ * N_ * N_ * sizeof(bf16);   // 67.1 MB
  if (ws_size < hwt_bytes + a16_bytes) return;  // ws proven sufficient in R1

  bf16* hwt = (bf16*)d_ws;
  bf16* a16 = (bf16*)((char*)d_ws + hwt_bytes);

  cvt_a_kernel<<<dim3(2048), dim3(256), 0, stream>>>(A, a16,
      (int)((size_t)B_ * N_ * N_ / 8));
  hwt_kernel<<<dim3(1024), dim3(256), 0, stream>>>(H, Wm, hwt);
  gemm8p_kernel<<<dim3(256), dim3(512), 0, stream>>>(a16, hwt, bias, out);
}